// Round 1
// baseline (644.918 us; speedup 1.0000x reference)
//
#include <hip/hip_runtime.h>
#include <math.h>

// LuongAttention: B=64, S=2048, D=1024
//   sims[b,s] = dot(enc[b,s,:], hid[b,:]); mask -> -inf; softmax over s;
//   out[b,d]  = sum_s attn[b,s] * enc[b,s,d]
// Flash-style single pass, ballot-bitmask mask skip, batch-of-4 rows:
//   - one __ballot per 64-row window replaces per-row mask loads
//   - 4 rows' loads issued together (16 dwordx4 in flight per lane)
//   - 4 interleaved shfl butterflies (serial-reduce latency amortized 4x)
//   - one online-softmax rescale per 4 rows instead of per row

constexpr int Bc = 64;
constexpr int Sc = 2048;
constexpr int Dc = 1024;

__device__ __forceinline__ float dot16(const float4& a, const float4& b,
                                       const float4& c, const float4& d,
                                       const float4& h0, const float4& h1,
                                       const float4& h2, const float4& h3)
{
    float p = a.x*h0.x + a.y*h0.y + a.z*h0.z + a.w*h0.w;
    p      += b.x*h1.x + b.y*h1.y + b.z*h1.z + b.w*h1.w;
    p      += c.x*h2.x + c.y*h2.y + c.z*h2.z + c.w*h2.w;
    p      += d.x*h3.x + d.y*h3.y + d.z*h3.z + d.w*h3.w;
    return p;
}

// Block = 256 threads = 4 waves. Lane j owns d-slots {4j..4j+3} at offsets
// +0,+256,+512,+768 (4 x float4). Wave states merged once per block via LDS.
// launch_bounds(256,3): ~170 VGPR cap so the batch-4 working set (~120 live
// VGPRs: 16 x-float4 + h + o) does not spill into the hot loop.
__global__ __launch_bounds__(256, 3)
void attn_partial(const int* __restrict__ mask,    // [B,S] 0/1 (1 = masked)
                  const float* __restrict__ enc,   // [B,S,D]
                  const float* __restrict__ hid,   // [B,D]
                  float* __restrict__ o_part,      // [B,SPLIT,D] (unnormalized)
                  float* __restrict__ ml_part,     // [B,SPLIT,2] (M, L)
                  float* __restrict__ out_final,   // [B,D] when SPLIT==1, else null
                  int SPLIT, int CHUNK)
{
    __shared__ float so[4][Dc];   // 16 KB: per-wave unnormalized context
    __shared__ float sm[4], sl[4];

    const int split = blockIdx.x;
    const int b     = blockIdx.y;
    const int tid   = threadIdx.x;
    const int wid   = tid >> 6;
    const int lane  = tid & 63;
    const int d0    = lane << 2;

    const float* hb = hid + (size_t)b * Dc;
    const float4 h0 = *(const float4*)(hb + d0);
    const float4 h1 = *(const float4*)(hb + d0 + 256);
    const float4 h2 = *(const float4*)(hb + d0 + 512);
    const float4 h3 = *(const float4*)(hb + d0 + 768);

    float4 o0 = make_float4(0.f,0.f,0.f,0.f);
    float4 o1 = o0, o2 = o0, o3 = o0;
    float m = -INFINITY, l = 0.f;

    const int rpw  = CHUNK >> 2;                  // rows per wave
    const int sbeg = split * CHUNK + wid * rpw;
    const int* mrow = mask + (size_t)b * Sc + sbeg;
    const float* ebase = enc + ((size_t)b * Sc + (size_t)sbeg) * Dc;

    for (int w0 = 0; w0 < rpw; w0 += 64) {
        const int nrem = rpw - w0;
        const int nwin = nrem < 64 ? nrem : 64;
        // bit i of bm <-> row w0+i unmasked (ballot bit index == lane)
        uint64_t bm = __ballot(lane < nwin && mrow[w0 + lane] == 0);

        while (bm) {
            // peel up to 4 set bits; dead slots replicate r0 (loads L1-hit,
            // p forced to -inf => weight 0, zero contribution)
            const int r0 = __builtin_ctzll(bm); bm &= bm - 1;
            int r1 = r0, r2 = r0, r3 = r0;
            bool v1 = false, v2 = false, v3 = false;
            if (bm) { v1 = true; r1 = __builtin_ctzll(bm); bm &= bm - 1; }
            if (bm) { v2 = true; r2 = __builtin_ctzll(bm); bm &= bm - 1; }
            if (bm) { v3 = true; r3 = __builtin_ctzll(bm); bm &= bm - 1; }

            const float* R0 = ebase + (size_t)(w0 + r0) * Dc + d0;
            const float* R1 = ebase + (size_t)(w0 + r1) * Dc + d0;
            const float* R2 = ebase + (size_t)(w0 + r2) * Dc + d0;
            const float* R3 = ebase + (size_t)(w0 + r3) * Dc + d0;

            // 16 independent dwordx4 loads in flight
            const float4 A0 = *(const float4*)(R0);       const float4 A1 = *(const float4*)(R0 + 256);
            const float4 A2 = *(const float4*)(R0 + 512); const float4 A3 = *(const float4*)(R0 + 768);
            const float4 B0 = *(const float4*)(R1);       const float4 B1 = *(const float4*)(R1 + 256);
            const float4 B2 = *(const float4*)(R1 + 512); const float4 B3 = *(const float4*)(R1 + 768);
            const float4 C0 = *(const float4*)(R2);       const float4 C1 = *(const float4*)(R2 + 256);
            const float4 C2 = *(const float4*)(R2 + 512); const float4 C3 = *(const float4*)(R2 + 768);
            const float4 D0 = *(const float4*)(R3);       const float4 D1 = *(const float4*)(R3 + 256);
            const float4 D2 = *(const float4*)(R3 + 512); const float4 D3 = *(const float4*)(R3 + 768);

            float p0 = dot16(A0,A1,A2,A3, h0,h1,h2,h3);
            float p1 = dot16(B0,B1,B2,B3, h0,h1,h2,h3);
            float p2 = dot16(C0,C1,C2,C3, h0,h1,h2,h3);
            float p3 = dot16(D0,D1,D2,D3, h0,h1,h2,h3);

            // 4 independent butterfly chains, interleaved per step
            #pragma unroll
            for (int off = 32; off > 0; off >>= 1) {
                p0 += __shfl_xor(p0, off, 64);
                p1 += __shfl_xor(p1, off, 64);
                p2 += __shfl_xor(p2, off, 64);
                p3 += __shfl_xor(p3, off, 64);
            }

            if (!v1) p1 = -INFINITY;
            if (!v2) p2 = -INFINITY;
            if (!v3) p3 = -INFINITY;

            const float pm = fmaxf(fmaxf(p0, p1), fmaxf(p2, p3));
            const float mn = fmaxf(m, pm);
            const float al = __expf(m - mn);        // 0 when m==-inf (mn finite)
            const float e0 = __expf(p0 - mn);
            const float e1 = __expf(p1 - mn);       // 0 for dead slots
            const float e2 = __expf(p2 - mn);
            const float e3 = __expf(p3 - mn);
            m = mn;
            l = l * al + (e0 + e1 + e2 + e3);

            // one rescale per 4 rows: o = o*al + sum_i e_i * x_i
            o0.x = o0.x*al + e0*A0.x + e1*B0.x + e2*C0.x + e3*D0.x;
            o0.y = o0.y*al + e0*A0.y + e1*B0.y + e2*C0.y + e3*D0.y;
            o0.z = o0.z*al + e0*A0.z + e1*B0.z + e2*C0.z + e3*D0.z;
            o0.w = o0.w*al + e0*A0.w + e1*B0.w + e2*C0.w + e3*D0.w;
            o1.x = o1.x*al + e0*A1.x + e1*B1.x + e2*C1.x + e3*D1.x;
            o1.y = o1.y*al + e0*A1.y + e1*B1.y + e2*C1.y + e3*D1.y;
            o1.z = o1.z*al + e0*A1.z + e1*B1.z + e2*C1.z + e3*D1.z;
            o1.w = o1.w*al + e0*A1.w + e1*B1.w + e2*C1.w + e3*D1.w;
            o2.x = o2.x*al + e0*A2.x + e1*B2.x + e2*C2.x + e3*D2.x;
            o2.y = o2.y*al + e0*A2.y + e1*B2.y + e2*C2.y + e3*D2.y;
            o2.z = o2.z*al + e0*A2.z + e1*B2.z + e2*C2.z + e3*D2.z;
            o2.w = o2.w*al + e0*A2.w + e1*B2.w + e2*C2.w + e3*D2.w;
            o3.x = o3.x*al + e0*A3.x + e1*B3.x + e2*C3.x + e3*D3.x;
            o3.y = o3.y*al + e0*A3.y + e1*B3.y + e2*C3.y + e3*D3.y;
            o3.z = o3.z*al + e0*A3.z + e1*B3.z + e2*C3.z + e3*D3.z;
            o3.w = o3.w*al + e0*A3.w + e1*B3.w + e2*C3.w + e3*D3.w;
        }
    }

    if (lane == 0) { sm[wid] = m; sl[wid] = l; }
    *(float4*)&so[wid][d0      ] = o0;
    *(float4*)&so[wid][d0 + 256] = o1;
    *(float4*)&so[wid][d0 + 512] = o2;
    *(float4*)&so[wid][d0 + 768] = o3;
    __syncthreads();

    // merge the 4 wave states (runs once per block; cost trivial)
    const float M  = fmaxf(fmaxf(sm[0], sm[1]), fmaxf(sm[2], sm[3]));
    // guard: a fully-masked wave has m=-inf; exp(-inf - -inf) would be NaN
    const float e0 = (sm[0] == -INFINITY) ? 0.f : __expf(sm[0] - M);
    const float e1 = (sm[1] == -INFINITY) ? 0.f : __expf(sm[1] - M);
    const float e2 = (sm[2] == -INFINITY) ? 0.f : __expf(sm[2] - M);
    const float e3 = (sm[3] == -INFINITY) ? 0.f : __expf(sm[3] - M);
    const float L  = sl[0]*e0 + sl[1]*e1 + sl[2]*e2 + sl[3]*e3;

    const int dd = tid << 2;   // thread t now owns d = 4t..4t+3
    const float4 v0 = *(float4*)&so[0][dd];
    const float4 v1 = *(float4*)&so[1][dd];
    const float4 v2 = *(float4*)&so[2][dd];
    const float4 v3 = *(float4*)&so[3][dd];
    float4 acc;
    acc.x = v0.x*e0 + v1.x*e1 + v2.x*e2 + v3.x*e3;
    acc.y = v0.y*e0 + v1.y*e1 + v2.y*e2 + v3.y*e3;
    acc.z = v0.z*e0 + v1.z*e1 + v2.z*e2 + v3.z*e3;
    acc.w = v0.w*e0 + v1.w*e1 + v2.w*e2 + v3.w*e3;

    if (out_final) {
        const float inv = (L > 0.f) ? 1.f / L : 0.f;
        acc.x *= inv; acc.y *= inv; acc.z *= inv; acc.w *= inv;
        *(float4*)&out_final[(size_t)b * Dc + dd] = acc;
    } else {
        *(float4*)&o_part[((size_t)b * SPLIT + split) * Dc + dd] = acc;
        if (tid == 0) {
            ml_part[((size_t)b * SPLIT + split) * 2    ] = M;
            ml_part[((size_t)b * SPLIT + split) * 2 + 1] = L;
        }
    }
}

// grid (4, B), 64 threads: block q reduces D-quarter q for batch b.
__global__ __launch_bounds__(64)
void attn_combine(const float* __restrict__ o_part,
                  const float* __restrict__ ml_part,
                  float* __restrict__ out, int SPLIT)
{
    __shared__ float sme[64], sle[64];
    const int b   = blockIdx.y;
    const int q   = blockIdx.x;
    const int tid = threadIdx.x;
    if (tid < SPLIT) {
        sme[tid] = ml_part[((size_t)b * SPLIT + tid) * 2];
        sle[tid] = ml_part[((size_t)b * SPLIT + tid) * 2 + 1];
    }
    __syncthreads();

    float M = -INFINITY;
    for (int s = 0; s < SPLIT; ++s) M = fmaxf(M, sme[s]);
    float L = 0.f;
    for (int s = 0; s < SPLIT; ++s)
        L += (sme[s] == -INFINITY) ? 0.f : sle[s] * __expf(sme[s] - M);

    const int dd = q * 256 + (tid << 2);
    float4 acc = make_float4(0.f,0.f,0.f,0.f);
    for (int s = 0; s < SPLIT; ++s) {
        const float e = (sme[s] == -INFINITY) ? 0.f : __expf(sme[s] - M);
        const float4 v = *(const float4*)&o_part[((size_t)b * SPLIT + s) * Dc + dd];
        acc.x += e * v.x; acc.y += e * v.y; acc.z += e * v.z; acc.w += e * v.w;
    }
    const float inv = (L > 0.f) ? 1.f / L : 0.f;
    acc.x *= inv; acc.y *= inv; acc.z *= inv; acc.w *= inv;
    *(float4*)&out[(size_t)b * Dc + dd] = acc;
}

extern "C" void kernel_launch(void* const* d_in, const int* in_sizes, int n_in,
                              void* d_out, int out_size, void* d_ws, size_t ws_size,
                              hipStream_t stream)
{
    const int*   mask = (const int*)d_in[0];    // bool mask, delivered as int32
    const float* enc  = (const float*)d_in[1];  // [B,S,D] fp32
    const float* hid  = (const float*)d_in[2];  // [B,D]   fp32
    float*       out  = (float*)d_out;          // [B,D]   fp32

    // choose largest split count whose partial buffers fit in d_ws
    int SPLIT = 32;
    while (SPLIT > 1 &&
           (size_t)Bc * SPLIT * (Dc + 2) * sizeof(float) > ws_size)
        SPLIT >>= 1;
    const bool direct =
        (SPLIT == 1) || ((size_t)Bc * (Dc + 2) * sizeof(float) > ws_size);
    if (direct) SPLIT = 1;

    float* o_part  = (float*)d_ws;
    float* ml_part = o_part + (size_t)Bc * SPLIT * Dc;

    attn_partial<<<dim3(SPLIT, Bc), 256, 0, stream>>>(
        mask, enc, hid,
        direct ? nullptr : o_part,
        direct ? nullptr : ml_part,
        direct ? out : nullptr,
        SPLIT, Sc / SPLIT);

    if (!direct)
        attn_combine<<<dim3(4, Bc), 64, 0, stream>>>(o_part, ml_part, out, SPLIT);
}